// Round 4
// baseline (200.899 us; speedup 1.0000x reference)
//
#include <hip/hip_runtime.h>

// Problem constants (from reference)
#define B_     256
#define M_     64
#define T_     1200
#define FT_    10
#define K_     17
#define PAD_   8
#define POOLK_ 75
#define POOLS_ 15
#define TP_    76            // pooled length
#define NSEG_  80            // T_/POOLS_ segments of 15
#define NPAIR_ (FT_*NSEG_)   // 800
#define FEAT_  (FT_*TP_)     // 760
#define XLEN_  (T_ + 2*PAD_) // 1216
#define NTH_   3             // j-thirds per segment
#define NJ_    5             // conv outputs per third
#define XV_    (NJ_ + K_ - 1) // 21-sample window per thread

__global__ __launch_bounds__(256, 4)
void ChannelScorer_Distributed_39024072851482_kernel(
    const float* __restrict__ x,      // (B,1,M,T) -> row-major (B*M, T)
    const float* __restrict__ conv_w, // (FT,1,K) = 170
    const float* __restrict__ conv_b, // (FT,)
    const float* __restrict__ lin_w,  // (M, FEAT)
    const float* __restrict__ lin_b,  // (M,)
    float* __restrict__ out)          // (B,M,1) -> 16384
{
    __shared__ float xs[XLEN_];          // 1216 padded row (4.9 KB)
    __shared__ float S3[NTH_][NPAIR_];   // per-third partial sums (9.6 KB)
    __shared__ float red[4];

    const int row = blockIdx.x;          // b*M_+m
    const int m   = row & (M_-1);
    const int tid = threadIdx.x;

    // ---- stage x row into LDS (padded with zeros) ----
    if (tid < PAD_)      xs[tid] = 0.f;
    if (tid >= 256-PAD_) xs[tid + (T_ + PAD_ - (256-PAD_))] = 0.f; // 1208..1215
    {
        const float4* xr = (const float4*)(x + (size_t)row * T_); // 16B aligned
        for (int i = tid; i < T_/4; i += 256)
            *(float4*)&xs[PAD_ + 4*i] = xr[i];
    }
    __syncthreads();

    // ---- conv + square + partial segment-sum ----
    // thread = (third tau, segment g); all 10 filters on a 5-output j-slice.
    // f is block-uniform -> conv_w reads are s_load (SGPR operand in v_fma).
    // The f-body is kept lgkm-QUIET: no ds ops between the s_loads and their
    // use (round-3 stall: ds_write S3 in-loop forced lgkmcnt(0) drains that
    // exposed scalar-load latency every iteration). S3 stores are deferred,
    // biases preloaded into pinned VGPRs, f-loop fully unrolled so the
    // compiler pipelines the 170 s_loads ahead of use.
    if (tid < NTH_*NSEG_) {              // 240 active
        const int tau = tid / NSEG_;     // 0..2
        const int g   = tid - tau*NSEG_; // 0..79
        const int base = POOLS_*g + NJ_*tau;

        float xv[XV_];
        #pragma unroll
        for (int u = 0; u < XV_; ++u) xv[u] = xs[base + u];
        // Opaque pin: prevents remat of the LDS window loads into the FMA loop
        // (round-0/2 failure mode) and clears lgkm before the scalar loads.
        #pragma unroll
        for (int u = 0; u < XV_; ++u) asm volatile("" : "+v"(xv[u]));

        // Biases in VGPRs (not SGPRs): v_fma takes w[k] as its single allowed
        // SGPR operand, bias as VGPR -> no per-j v_mov init.
        float bv[FT_];
        #pragma unroll
        for (int f = 0; f < FT_; ++f) bv[f] = conv_b[f];
        #pragma unroll
        for (int f = 0; f < FT_; ++f) asm volatile("" : "+v"(bv[f]));

        float part[FT_];                 // static indices only (full unroll)
        #pragma unroll
        for (int f = 0; f < FT_; ++f) {
            float w[K_];
            #pragma unroll
            for (int k = 0; k < K_; ++k) w[k] = conv_w[f*K_ + k]; // uniform -> s_load
            float p = 0.f;
            #pragma unroll
            for (int jj = 0; jj < NJ_; ++jj) {
                float acc = fmaf(xv[jj], w[0], bv[f]);
                #pragma unroll
                for (int k = 1; k < K_; ++k)
                    acc = fmaf(xv[jj + k], w[k], acc);
                p = fmaf(acc, acc, p);
            }
            part[f] = p;
        }

        // deferred stores: consecutive lanes -> consecutive addrs
        #pragma unroll
        for (int f = 0; f < FT_; ++f)
            S3[tau][f*NSEG_ + g] = part[f];
    }
    __syncthreads();

    // ---- combine thirds in place: S3[0][i] = sum_tau S3[tau][i] ----
    for (int i = tid; i < NPAIR_; i += 256)
        S3[0][i] = S3[0][i] + S3[1][i] + S3[2][i];
    __syncthreads();

    // ---- pool(5 segs) -> log -> dot with lin_w[m,:] ----
    float partial = 0.f;
    const float* lw = lin_w + (size_t)m * FEAT_;
    for (int i = tid; i < FEAT_; i += 256) {
        const int f = i / TP_;            // 0..9
        const int p = i - f * TP_;        // 0..75
        const float* Sp = &S3[0][f*NSEG_ + p];
        float v = (Sp[0] + Sp[1] + Sp[2] + Sp[3] + Sp[4]) * (1.0f/POOLK_);
        v = fmaxf(v, 1e-10f);
        partial = fmaf(__logf(v), lw[i], partial);
    }

    // ---- block reduction ----
    #pragma unroll
    for (int off = 32; off > 0; off >>= 1)
        partial += __shfl_down(partial, off, 64);
    const int wave = tid >> 6, lane = tid & 63;
    if (lane == 0) red[wave] = partial;
    __syncthreads();
    if (tid == 0)
        out[row] = red[0] + red[1] + red[2] + red[3] + lin_b[m];
}

extern "C" void kernel_launch(void* const* d_in, const int* in_sizes, int n_in,
                              void* d_out, int out_size, void* d_ws, size_t ws_size,
                              hipStream_t stream) {
    const float* x      = (const float*)d_in[0];
    const float* conv_w = (const float*)d_in[1];
    const float* conv_b = (const float*)d_in[2];
    const float* lin_w  = (const float*)d_in[3];
    const float* lin_b  = (const float*)d_in[4];
    float* out = (float*)d_out;

    dim3 grid(B_ * M_);             // 16384 blocks, 1 row each
    dim3 block(256);                // 4 waves
    ChannelScorer_Distributed_39024072851482_kernel<<<grid, block, 0, stream>>>(
        x, conv_w, conv_b, lin_w, lin_b, out);
}